// Round 2
// baseline (448.770 us; speedup 1.0000x reference)
//
#include <hip/hip_runtime.h>
#include <hip/hip_bf16.h>
#include <hip/hip_fp16.h>

// Problem constants
#define BATCH 4
#define SEQ   2048
#define HID   1024
#define HEADS 16
#define HDIM  64
#define MROWS (BATCH * SEQ)   // 8192
#define LOG2E 1.4426950408889634f
#define SCL   (LOG2E / 8.0f)  // log2e / sqrt(HDIM)

typedef _Float16 v8h __attribute__((ext_vector_type(8)));
typedef _Float16 v4h __attribute__((ext_vector_type(4)));
typedef _Float16 v2h __attribute__((ext_vector_type(2)));
typedef float    v4f __attribute__((ext_vector_type(4)));
typedef int      v4i __attribute__((ext_vector_type(4)));

#define MFMA16(a, b, c) __builtin_amdgcn_mfma_f32_16x16x32_f16((a), (b), (c), 0, 0, 0)
// 16x16x16 f16 MFMA: A-frag layout (m=lane&15, k=quad*4+j) == S^T C/D layout,
// so exp(S^T) packs directly into PV A-fragments with NO LDS round-trip.
#define MFMA16K16(a, b, c) __builtin_amdgcn_mfma_f32_16x16x16f16((a), (b), (c), 0, 0, 0)

__device__ inline int pk2(float a, float b) {
    return __builtin_bit_cast(int, __builtin_amdgcn_cvt_pkrtz(a, b));
}

// async global->LDS, 16B per lane; dest = wave-uniform base + lane*16
__device__ __forceinline__ void async16(const void* g, void* l) {
    __builtin_amdgcn_global_load_lds(
        (const __attribute__((address_space(1))) unsigned int*)g,
        (__attribute__((address_space(3))) unsigned int*)l, 16, 0, 0);
}

// swizzled LDS element offset for a 64-elem (128B) row: 16B chunk ^= row&7
#define SWZ(row, chunk) (((row) * 64) + ((((chunk) ^ ((row) & 7))) * 8))

// ---------------- fused prep: cvt_x (bid<4096) + transw (bid>=4096) -----
// cvt_x: x f32 -> f16, 8 elems/thread.
// transw: W [K][N] f32 -> Wt [N][K] f16 (3 mats).
__global__ __launch_bounds__(256) void prep(
    const float* __restrict__ x, _Float16* __restrict__ xb,
    const float* __restrict__ W0, const float* __restrict__ W1,
    const float* __restrict__ W2, _Float16* __restrict__ Wt) {
    __shared__ float t[32][33];
    const int bid = blockIdx.x;
    const int tid = threadIdx.x;
    if (bid < 4096) {
        int i = bid * 256 + tid;     // one thread = 8 elems
        const float4* xp = (const float4*)x;
        float4 a = xp[2 * i];
        float4 b = xp[2 * i + 1];
        v4i o;
        o[0] = pk2(a.x, a.y); o[1] = pk2(a.z, a.w);
        o[2] = pk2(b.x, b.y); o[3] = pk2(b.z, b.w);
        ((v4i*)xb)[i] = o;
    } else {
        int tt = bid - 4096;                 // 0..3071
        int z = tt >> 10;
        int rem = tt & 1023;
        const float* W = (z == 0) ? W0 : (z == 1 ? W1 : W2);
        _Float16* dst = Wt + (size_t)z * HID * HID;
        int bx = (rem & 31) * 32, by = (rem >> 5) * 32;
        int tx = tid & 31, ty = tid >> 5;    // (32, 8)
#pragma unroll
        for (int i = 0; i < 4; i++)
            t[ty + i * 8][tx] = W[(size_t)(by + ty + i * 8) * HID + bx + tx];
        __syncthreads();
#pragma unroll
        for (int i = 0; i < 4; i++)
            dst[(size_t)(bx + ty + i * 8) * HID + by + tx] = (_Float16)t[tx][ty + i * 8];
    }
}

// ---------------- fused QKV GEMM + bias build ---------------------------
// bid < 1536 : QKV projection GEMM (f16, async swizzled staging), mode=bid>>9
// bid >= 1536: mkbias — permuted bias (MFMA S^T fragment order, f16)
//   biasT[b][K16][Q16][lane][r] = mask ? -|a|*log2e*t : -57344
//   (k = K16*16 + (lane>>4)*4 + r, q = Q16*16 + (lane&15))
// gemm blocks at low bids dispatch first (compute-critical); memory-bound
// bias blocks stream into CU slots / HBM BW behind them.
__global__ __launch_bounds__(256) void gemm_bias(
    const _Float16* __restrict__ xb, const _Float16* __restrict__ wt,
    const float* __restrict__ bq, const float* __restrict__ bk,
    const float* __restrict__ bv,
    _Float16* __restrict__ Qb, _Float16* __restrict__ Kb, _Float16* __restrict__ Vtb,
    const float* __restrict__ tiv, const int* __restrict__ msk,
    const float* __restrict__ alphap, _Float16* __restrict__ biasT) {
    __shared__ _Float16 smem[2 * 128 * 64];     // gemm: As+Bs; bias: L (4224)
    const int bid = blockIdx.x;
    const int tid = threadIdx.x;

    if (bid < 1536) {
        // ---------------- GEMM path ----------------
        const int mode = bid >> 9;
        const int within = bid & 511;
        const int n0 = (within & 7) * 128;
        const int m0 = (within >> 3) * 128;
        const _Float16* w = wt + (size_t)mode * HID * HID;
        _Float16* As = smem;
        _Float16* Bs = smem + 128 * 64;
        const int wv = tid >> 6, lane = tid & 63;
        const int quad = lane >> 4, l15 = lane & 15;
        const int wr = wv >> 1, wc = wv & 1;

        v4f acc[4][4];
#pragma unroll
        for (int i = 0; i < 4; i++)
#pragma unroll
            for (int j = 0; j < 4; j++) acc[i][j] = (v4f){0.f, 0.f, 0.f, 0.f};

        const int srow = lane >> 3;         // 0..7 within 8-row chunk
        const int schk = lane & 7;          // 16B chunk within row
        const _Float16* Ag = xb + (size_t)m0 * HID;
        const _Float16* Bg = w + (size_t)n0 * HID;

        for (int k0 = 0; k0 < HID; k0 += 64) {
            __syncthreads();
#pragma unroll
            for (int i = 0; i < 4; i++) {
                int ra = wv * 32 + i * 8 + srow;            // 0..127
                int ca = schk ^ (ra & 7);
                async16(Ag + (size_t)ra * HID + k0 + ca * 8, &As[(wv * 32 + i * 8) * 64]);
                async16(Bg + (size_t)ra * HID + k0 + ca * 8, &Bs[(wv * 32 + i * 8) * 64]);
            }
            __syncthreads();
#pragma unroll
            for (int kc = 0; kc < 2; kc++) {
                v8h af[4], bf[4];
#pragma unroll
                for (int t = 0; t < 4; t++) {
                    af[t] = *(const v8h*)&As[SWZ(wr * 64 + t * 16 + l15, kc * 4 + quad)];
                    bf[t] = *(const v8h*)&Bs[SWZ(wc * 64 + t * 16 + l15, kc * 4 + quad)];
                }
                __builtin_amdgcn_s_setprio(1);
#pragma unroll
                for (int tm = 0; tm < 4; tm++)
#pragma unroll
                    for (int tn = 0; tn < 4; tn++)
                        acc[tm][tn] = MFMA16(af[tm], bf[tn], acc[tm][tn]);
                __builtin_amdgcn_s_setprio(0);
            }
        }

        const float* pb = (mode == 0) ? bq : (mode == 1 ? bk : bv);
        const float oscl = (mode == 0) ? SCL : 1.0f;   // fold log2e/8 into Q
#pragma unroll
        for (int tm = 0; tm < 4; tm++) {
#pragma unroll
            for (int tn = 0; tn < 4; tn++) {
                int n = n0 + wc * 64 + tn * 16 + l15;
                float bval = pb[n];
                int h = n >> 6, d = n & 63;
#pragma unroll
                for (int r = 0; r < 4; r++) {
                    int m = m0 + wr * 64 + tm * 16 + quad * 4 + r;
                    int b = m >> 11, s = m & 2047;
                    _Float16 hv = (_Float16)((acc[tm][tn][r] + bval) * oscl);
                    if (mode == 2) {
                        Vtb[(((size_t)(b * HEADS + h) * HDIM + d) * SEQ) + s] = hv;
                    } else {
                        _Float16* dst = (mode == 0) ? Qb : Kb;
                        dst[((size_t)(b * HEADS + h) * SEQ + s) * HDIM + d] = hv;
                    }
                }
            }
        }
    } else {
        // ---------------- mkbias path ----------------
        const int t = bid - 1536;                 // 0..4095
        const int kc0 = (t & 7) * 256;
        const int Q16 = (t >> 3) & 127;
        const int b = t >> 10;
        _Float16* L = smem;                        // 16*264 elems
        const float ca = -fabsf(alphap[0]) * LOG2E;
        const int prow = tid >> 6;          // 0..3
        const int pcol = (tid & 63) * 4;    // 0..252
#pragma unroll
        for (int pi = 0; pi < 4; pi++) {
            int r = pi * 4 + prow;
            size_t g = ((size_t)b * SEQ + Q16 * 16 + r) * SEQ + kc0 + pcol;
            float4 tv = *(const float4*)(tiv + g);
            int4   mv = *(const int4*)(msk + g);
            float f0 = mv.x ? ca * tv.x : -57344.0f;
            float f1 = mv.y ? ca * tv.y : -57344.0f;
            float f2 = mv.z ? ca * tv.z : -57344.0f;
            float f3 = mv.w ? ca * tv.w : -57344.0f;
            int2 o; o.x = pk2(f0, f1); o.y = pk2(f2, f3);
            *(int2*)&L[r * 264 + pcol] = o;
        }
        __syncthreads();
        const int lane = tid & 63, tq = tid >> 6;
#pragma unroll
        for (int it = 0; it < 4; it++) {
            int K16i = it * 4 + tq;
            int kl = K16i * 16 + (lane >> 4) * 4;
            int qr = lane & 15;
            int2 v = *(const int2*)&L[qr * 264 + kl];
            size_t o = ((((size_t)b * 128 + (kc0 >> 4) + K16i) * 128 + Q16) * 64 + lane) * 4;
            *(int2*)&biasT[o] = v;
        }
    }
}

// ---------------- flash attention (S^T, P stays in registers) -----------
// grid (16 q-tiles, 64 b*h); block 256 (4 waves); wave owns 32 q-rows.
// 2-phase pipeline: K/V double-buffered in LDS, next tile's async16 +
// bias register loads issued BEFORE current tile's compute; ONE barrier
// per K-tile (its vmcnt(0) drain doubles as the pipeline wait).
// XCD-aware remap keeps all 16 q-tiles of a bh on one XCD (K+V = 4 MB/XCD).
__global__ __launch_bounds__(256, 4) void attn(
    const _Float16* __restrict__ Qb, const _Float16* __restrict__ Kb,
    const _Float16* __restrict__ Vtb, const _Float16* __restrict__ biasT,
    float* __restrict__ out) {
    const int wg  = (blockIdx.y << 4) | blockIdx.x;   // linear dispatch id
    const int nid = ((wg & 7) << 7) | (wg >> 3);      // bijective: 128 wg/XCD
    const int bh = nid >> 4;
    const int qt = nid & 15;
    const int b = bh >> 4, h = bh & 15;
    const int tid = threadIdx.x;
    const int wv = tid >> 6, lane = tid & 63;
    const int quad = lane >> 4, l15 = lane & 15;

    __shared__ _Float16 Ks[2][64 * 64];   // [buf][key][d], swizzled
    __shared__ _Float16 Vs[2][64 * 64];   // [buf][d][key], swizzled

    const int q0 = qt * 128 + wv * 32;
    const int Q16a = q0 >> 4;             // + tm

    const _Float16* Qp = Qb + (size_t)(b * HEADS + h) * SEQ * HDIM;
    const _Float16* Kp = Kb + (size_t)(b * HEADS + h) * SEQ * HDIM;
    const _Float16* Vp = Vtb + (size_t)(b * HEADS + h) * HDIM * SEQ;
    const _Float16* Bbase = biasT + (size_t)b * 128 * 128 * 64 * 4;

    // Q fragments (B-operand: lane l15 = qrow, k = d); Q is pre-scaled by SCL
    v8h qf[2][2];
#pragma unroll
    for (int tm = 0; tm < 2; tm++)
#pragma unroll
        for (int kc = 0; kc < 2; kc++)
            qf[tm][kc] = *(const v8h*)&Qp[(size_t)(q0 + tm * 16 + l15) * HDIM + kc * 32 + quad * 8];

    v4f oacc[2][4];
#pragma unroll
    for (int i = 0; i < 2; i++)
#pragma unroll
        for (int j = 0; j < 4; j++) oacc[i][j] = (v4f){0.f, 0.f, 0.f, 0.f};
    float lsum[2] = {0.f, 0.f};

    const int srow = lane >> 3, schk = lane & 7;

#define STAGE(buf_, key0_)                                                  \
    {                                                                       \
        _Pragma("unroll")                                                   \
        for (int i_ = 0; i_ < 2; i_++) {                                    \
            int r_ = wv * 16 + i_ * 8 + srow;                               \
            int c_ = schk ^ (r_ & 7);                                       \
            async16(Kp + (size_t)((key0_) + r_) * HDIM + c_ * 8,            \
                    &Ks[buf_][(wv * 16 + i_ * 8) * 64]);                    \
            async16(Vp + (size_t)r_ * SEQ + (key0_) + c_ * 8,               \
                    &Vs[buf_][(wv * 16 + i_ * 8) * 64]);                    \
        }                                                                   \
    }

#define BLOAD(key0_)                                                        \
    {                                                                       \
        _Pragma("unroll")                                                   \
        for (int nt_ = 0; nt_ < 4; nt_++)                                   \
            _Pragma("unroll")                                               \
            for (int tm_ = 0; tm_ < 2; tm_++)                               \
                bl[nt_][tm_] = *(const int2*)&Bbase[((((size_t)((key0_) >> 4) + nt_) * 128 + Q16a + tm_) * 64 + lane) * 4]; \
    }

    int2 bl[4][2];
    STAGE(0, 0)
    BLOAD(0)
    __syncthreads();     // vmcnt(0) drain: tile 0 + bias 0 in flight -> ready

    for (int kt = 0; kt < SEQ / 64; kt++) {
        const int cur = kt & 1;
        const int key0 = kt * 64;

        // consume bias regs -> accumulator init (f16 pre-multiplied by log2e)
        v4f sacc[4][2];
#pragma unroll
        for (int nt = 0; nt < 4; nt++)
#pragma unroll
            for (int tm = 0; tm < 2; tm++) {
                v4h bv = __builtin_bit_cast(v4h, bl[nt][tm]);
                sacc[nt][tm] = (v4f){(float)bv[0], (float)bv[1], (float)bv[2], (float)bv[3]};
            }

        // prefetch NEXT tile under current compute: K/V -> LDS buf^1 (async),
        // bias -> regs (bl just died into sacc). Latency hides under MFMAs.
        if (kt + 1 < SEQ / 64) {
            STAGE(cur ^ 1, key0 + 64)
            BLOAD(key0 + 64)
        }

        // S^T = K Q^T + bias : C/D row = key (quad*4+r), col = qrow (l15)
#pragma unroll
        for (int kc = 0; kc < 2; kc++) {
            v8h kfr[4];
#pragma unroll
            for (int nt = 0; nt < 4; nt++)
                kfr[nt] = *(const v8h*)&Ks[cur][SWZ(nt * 16 + l15, kc * 4 + quad)];
            __builtin_amdgcn_s_setprio(1);
#pragma unroll
            for (int nt = 0; nt < 4; nt++)
#pragma unroll
                for (int tm = 0; tm < 2; tm++)
                    sacc[nt][tm] = MFMA16(kfr[nt], qf[tm][kc], sacc[nt][tm]);
            __builtin_amdgcn_s_setprio(0);
        }

        // p = exp2(sacc); pack pairs -> PV A-fragments (in registers!)
        int2 pfr[4][2];   // [key-16-tile][tm]: 4 f16, k = quad*4 + j
#pragma unroll
        for (int nt = 0; nt < 4; nt++)
#pragma unroll
            for (int tm = 0; tm < 2; tm++) {
                float p0 = __builtin_amdgcn_exp2f(sacc[nt][tm][0]);
                float p1 = __builtin_amdgcn_exp2f(sacc[nt][tm][1]);
                float p2 = __builtin_amdgcn_exp2f(sacc[nt][tm][2]);
                float p3 = __builtin_amdgcn_exp2f(sacc[nt][tm][3]);
                int2 pkv;
                pkv.x = pk2(p0, p1);
                pkv.y = pk2(p2, p3);
                lsum[tm] += (p0 + p1) + (p2 + p3);
                pfr[nt][tm] = pkv;
            }

        // O += P V via 16x16x16: A = pfr (regs), B = V^T b64 frags from LDS
        // (B-frag: lane l15 = d, k = g*16 + quad*4 + j)
#pragma unroll
        for (int g = 0; g < 4; g++) {
            v4h vfr[4];
#pragma unroll
            for (int nt = 0; nt < 4; nt++) {
                int row = nt * 16 + l15;                       // d
                int cc = g * 2 + (quad >> 1);                  // 16B chunk
                vfr[nt] = *(const v4h*)&Vs[cur][row * 64 + ((cc ^ (row & 7)) * 8) + (quad & 1) * 4];
            }
            __builtin_amdgcn_s_setprio(1);
#pragma unroll
            for (int tm = 0; tm < 2; tm++) {
                v4h pa = __builtin_bit_cast(v4h, pfr[g][tm]);
#pragma unroll
                for (int nt = 0; nt < 4; nt++)
                    oacc[tm][nt] = MFMA16K16(pa, vfr[nt], oacc[tm][nt]);
            }
            __builtin_amdgcn_s_setprio(0);
        }

        // ONE barrier per tile: compiler emits s_waitcnt vmcnt(0) lgkmcnt(0)
        // before s_barrier -> prefetch writes landed AND all waves done
        // reading buf[cur]; buf[cur] is then safe to overwrite next iter.
        __syncthreads();
    }

#undef STAGE
#undef BLOAD

    // epilogue: reduce row sums across quads, fetch per-C/D-row inverse, store
#pragma unroll
    for (int tm = 0; tm < 2; tm++) {
        float lt = lsum[tm];
        lt += __shfl_xor(lt, 16);
        lt += __shfl_xor(lt, 32);
        float inv[4];
#pragma unroll
        for (int r = 0; r < 4; r++)
            inv[r] = 1.0f / __shfl(lt, quad * 4 + r);
#pragma unroll
        for (int nt = 0; nt < 4; nt++)
#pragma unroll
            for (int r = 0; r < 4; r++) {
                int q = q0 + tm * 16 + quad * 4 + r;
                int d = nt * 16 + l15;
                out[((size_t)b * SEQ + q) * HID + h * HDIM + d] = oacc[tm][nt][r] * inv[r];
            }
    }
}

// ---------------- launch ----------------
extern "C" void kernel_launch(void* const* d_in, const int* in_sizes, int n_in,
                              void* d_out, int out_size, void* d_ws, size_t ws_size,
                              hipStream_t stream) {
    const float* x    = (const float*)d_in[0];
    const float* tiv  = (const float*)d_in[1];
    const int*   msk  = (const int*)d_in[2];
    const float* Wq   = (const float*)d_in[3];
    const float* bq   = (const float*)d_in[4];
    const float* Wk   = (const float*)d_in[5];
    const float* bk   = (const float*)d_in[6];
    const float* Wv   = (const float*)d_in[7];
    const float* bv   = (const float*)d_in[8];
    const float* alp  = (const float*)d_in[9];

    char* ws = (char*)d_ws;
    const size_t XB_OFF = 0;                                  // 16,777,216 B
    const size_t WT_OFF = XB_OFF + (size_t)MROWS * HID * 2;   // + 6,291,456 B
    const size_t Q_OFF  = WT_OFF + (size_t)3 * HID * HID * 2;
    const size_t K_OFF  = Q_OFF + (size_t)MROWS * HID * 2;
    const size_t V_OFF  = K_OFF + (size_t)MROWS * HID * 2;
    const size_t B_OFF  = V_OFF + (size_t)MROWS * HID * 2;    // biasT: 33,554,432 B

    _Float16* xb   = (_Float16*)(ws + XB_OFF);
    _Float16* wt   = (_Float16*)(ws + WT_OFF);
    _Float16* Qb   = (_Float16*)(ws + Q_OFF);
    _Float16* Kb   = (_Float16*)(ws + K_OFF);
    _Float16* Vtb  = (_Float16*)(ws + V_OFF);
    _Float16* bias = (_Float16*)(ws + B_OFF);

    prep<<<4096 + 3072, 256, 0, stream>>>(x, xb, Wq, Wk, Wv, wt);
    gemm_bias<<<1536 + 4096, 256, 0, stream>>>(xb, wt, bq, bk, bv, Qb, Kb, Vtb,
                                               tiv, msk, alp, bias);
    attn<<<dim3(SEQ / 128, BATCH * HEADS), 256, 0, stream>>>(Qb, Kb, Vtb, bias,
                                                             (float*)d_out);
}

// Round 3
// 376.503 us; speedup vs baseline: 1.1919x; 1.1919x over previous
//
#include <hip/hip_runtime.h>
#include <hip/hip_bf16.h>
#include <hip/hip_fp16.h>

// Problem constants
#define BATCH 4
#define SEQ   2048
#define HID   1024
#define HEADS 16
#define HDIM  64
#define MROWS (BATCH * SEQ)   // 8192
#define LOG2E 1.4426950408889634f
#define SCL   (LOG2E / 8.0f)  // log2e / sqrt(HDIM)

typedef _Float16 v8h __attribute__((ext_vector_type(8)));
typedef _Float16 v4h __attribute__((ext_vector_type(4)));
typedef _Float16 v2h __attribute__((ext_vector_type(2)));
typedef float    v4f __attribute__((ext_vector_type(4)));
typedef int      v4i __attribute__((ext_vector_type(4)));

#define MFMA16(a, b, c) __builtin_amdgcn_mfma_f32_16x16x32_f16((a), (b), (c), 0, 0, 0)
// 16x16x16 f16 MFMA: A-frag layout (m=lane&15, k=quad*4+j) == S^T C/D layout,
// so exp(S^T) packs directly into PV A-fragments with NO LDS round-trip.
#define MFMA16K16(a, b, c) __builtin_amdgcn_mfma_f32_16x16x16f16((a), (b), (c), 0, 0, 0)

__device__ inline int pk2(float a, float b) {
    return __builtin_bit_cast(int, __builtin_amdgcn_cvt_pkrtz(a, b));
}

// async global->LDS, 16B per lane; dest = wave-uniform base + lane*16
__device__ __forceinline__ void async16(const void* g, void* l) {
    __builtin_amdgcn_global_load_lds(
        (const __attribute__((address_space(1))) unsigned int*)g,
        (__attribute__((address_space(3))) unsigned int*)l, 16, 0, 0);
}

// swizzled LDS element offset for a 64-elem (128B) row: 16B chunk ^= row&7
#define SWZ(row, chunk) (((row) * 64) + ((((chunk) ^ ((row) & 7))) * 8))

// ---------------- fused prep: cvt_x (bid<4096) + transw (bid>=4096) -----
// cvt_x: x f32 -> f16, 8 elems/thread.
// transw: W [K][N] f32 -> Wt [N][K] f16 (3 mats).
__global__ __launch_bounds__(256) void prep(
    const float* __restrict__ x, _Float16* __restrict__ xb,
    const float* __restrict__ W0, const float* __restrict__ W1,
    const float* __restrict__ W2, _Float16* __restrict__ Wt) {
    __shared__ float t[32][33];
    const int bid = blockIdx.x;
    const int tid = threadIdx.x;
    if (bid < 4096) {
        int i = bid * 256 + tid;     // one thread = 8 elems
        const float4* xp = (const float4*)x;
        float4 a = xp[2 * i];
        float4 b = xp[2 * i + 1];
        v4i o;
        o[0] = pk2(a.x, a.y); o[1] = pk2(a.z, a.w);
        o[2] = pk2(b.x, b.y); o[3] = pk2(b.z, b.w);
        ((v4i*)xb)[i] = o;
    } else {
        int tt = bid - 4096;                 // 0..3071
        int z = tt >> 10;
        int rem = tt & 1023;
        const float* W = (z == 0) ? W0 : (z == 1 ? W1 : W2);
        _Float16* dst = Wt + (size_t)z * HID * HID;
        int bx = (rem & 31) * 32, by = (rem >> 5) * 32;
        int tx = tid & 31, ty = tid >> 5;    // (32, 8)
#pragma unroll
        for (int i = 0; i < 4; i++)
            t[ty + i * 8][tx] = W[(size_t)(by + ty + i * 8) * HID + bx + tx];
        __syncthreads();
#pragma unroll
        for (int i = 0; i < 4; i++)
            dst[(size_t)(bx + ty + i * 8) * HID + by + tx] = (_Float16)t[tx][ty + i * 8];
    }
}

// ---------------- fused QKV GEMM + bias build ---------------------------
// bid < 1536 : QKV projection GEMM (f16, async swizzled staging), mode=bid>>9
// bid >= 1536: mkbias — permuted bias (MFMA S^T fragment order, f16)
//   biasT[b][K16][Q16][lane][r] = mask ? -|a|*log2e*t : -57344
//   (k = K16*16 + (lane>>4)*4 + r, q = Q16*16 + (lane&15))
// gemm blocks at low bids dispatch first (compute-critical); memory-bound
// bias blocks stream into CU slots / HBM BW behind them.
__global__ __launch_bounds__(256) void gemm_bias(
    const _Float16* __restrict__ xb, const _Float16* __restrict__ wt,
    const float* __restrict__ bq, const float* __restrict__ bk,
    const float* __restrict__ bv,
    _Float16* __restrict__ Qb, _Float16* __restrict__ Kb, _Float16* __restrict__ Vtb,
    const float* __restrict__ tiv, const int* __restrict__ msk,
    const float* __restrict__ alphap, _Float16* __restrict__ biasT) {
    __shared__ _Float16 smem[2 * 128 * 64];     // gemm: As+Bs; bias: L (4224)
    const int bid = blockIdx.x;
    const int tid = threadIdx.x;

    if (bid < 1536) {
        // ---------------- GEMM path ----------------
        const int mode = bid >> 9;
        const int within = bid & 511;
        const int n0 = (within & 7) * 128;
        const int m0 = (within >> 3) * 128;
        const _Float16* w = wt + (size_t)mode * HID * HID;
        _Float16* As = smem;
        _Float16* Bs = smem + 128 * 64;
        const int wv = tid >> 6, lane = tid & 63;
        const int quad = lane >> 4, l15 = lane & 15;
        const int wr = wv >> 1, wc = wv & 1;

        v4f acc[4][4];
#pragma unroll
        for (int i = 0; i < 4; i++)
#pragma unroll
            for (int j = 0; j < 4; j++) acc[i][j] = (v4f){0.f, 0.f, 0.f, 0.f};

        const int srow = lane >> 3;         // 0..7 within 8-row chunk
        const int schk = lane & 7;          // 16B chunk within row
        const _Float16* Ag = xb + (size_t)m0 * HID;
        const _Float16* Bg = w + (size_t)n0 * HID;

        for (int k0 = 0; k0 < HID; k0 += 64) {
            __syncthreads();
#pragma unroll
            for (int i = 0; i < 4; i++) {
                int ra = wv * 32 + i * 8 + srow;            // 0..127
                int ca = schk ^ (ra & 7);
                async16(Ag + (size_t)ra * HID + k0 + ca * 8, &As[(wv * 32 + i * 8) * 64]);
                async16(Bg + (size_t)ra * HID + k0 + ca * 8, &Bs[(wv * 32 + i * 8) * 64]);
            }
            __syncthreads();
#pragma unroll
            for (int kc = 0; kc < 2; kc++) {
                v8h af[4], bf[4];
#pragma unroll
                for (int t = 0; t < 4; t++) {
                    af[t] = *(const v8h*)&As[SWZ(wr * 64 + t * 16 + l15, kc * 4 + quad)];
                    bf[t] = *(const v8h*)&Bs[SWZ(wc * 64 + t * 16 + l15, kc * 4 + quad)];
                }
#pragma unroll
                for (int tm = 0; tm < 4; tm++)
#pragma unroll
                    for (int tn = 0; tn < 4; tn++)
                        acc[tm][tn] = MFMA16(af[tm], bf[tn], acc[tm][tn]);
            }
        }

        const float* pb = (mode == 0) ? bq : (mode == 1 ? bk : bv);
        const float oscl = (mode == 0) ? SCL : 1.0f;   // fold log2e/8 into Q
#pragma unroll
        for (int tm = 0; tm < 4; tm++) {
#pragma unroll
            for (int tn = 0; tn < 4; tn++) {
                int n = n0 + wc * 64 + tn * 16 + l15;
                float bval = pb[n];
                int h = n >> 6, d = n & 63;
#pragma unroll
                for (int r = 0; r < 4; r++) {
                    int m = m0 + wr * 64 + tm * 16 + quad * 4 + r;
                    int b = m >> 11, s = m & 2047;
                    _Float16 hv = (_Float16)((acc[tm][tn][r] + bval) * oscl);
                    if (mode == 2) {
                        Vtb[(((size_t)(b * HEADS + h) * HDIM + d) * SEQ) + s] = hv;
                    } else {
                        _Float16* dst = (mode == 0) ? Qb : Kb;
                        dst[((size_t)(b * HEADS + h) * SEQ + s) * HDIM + d] = hv;
                    }
                }
            }
        }
    } else {
        // ---------------- mkbias path ----------------
        const int t = bid - 1536;                 // 0..4095
        const int kc0 = (t & 7) * 256;
        const int Q16 = (t >> 3) & 127;
        const int b = t >> 10;
        _Float16* L = smem;                        // 16*264 elems
        const float ca = -fabsf(alphap[0]) * LOG2E;
        const int prow = tid >> 6;          // 0..3
        const int pcol = (tid & 63) * 4;    // 0..252
#pragma unroll
        for (int pi = 0; pi < 4; pi++) {
            int r = pi * 4 + prow;
            size_t g = ((size_t)b * SEQ + Q16 * 16 + r) * SEQ + kc0 + pcol;
            float4 tv = *(const float4*)(tiv + g);
            int4   mv = *(const int4*)(msk + g);
            float f0 = mv.x ? ca * tv.x : -57344.0f;
            float f1 = mv.y ? ca * tv.y : -57344.0f;
            float f2 = mv.z ? ca * tv.z : -57344.0f;
            float f3 = mv.w ? ca * tv.w : -57344.0f;
            int2 o; o.x = pk2(f0, f1); o.y = pk2(f2, f3);
            *(int2*)&L[r * 264 + pcol] = o;
        }
        __syncthreads();
        const int lane = tid & 63, tq = tid >> 6;
#pragma unroll
        for (int it = 0; it < 4; it++) {
            int K16i = it * 4 + tq;
            int kl = K16i * 16 + (lane >> 4) * 4;
            int qr = lane & 15;
            int2 v = *(const int2*)&L[qr * 264 + kl];
            size_t o = ((((size_t)b * 128 + (kc0 >> 4) + K16i) * 128 + Q16) * 64 + lane) * 4;
            *(int2*)&biasT[o] = v;
        }
    }
}

// ---------------- flash attention (S^T, P stays in registers) -----------
// grid (16 q-tiles, 64 b*h); block 256 (4 waves); wave owns 32 q-rows.
// 2-phase pipeline: K/V double-buffered in LDS, next tile's async16 +
// bias register loads issued BEFORE current tile's compute; ONE barrier
// per K-tile (its vmcnt(0) drain doubles as the pipeline wait).
// XCD-aware remap keeps all 16 q-tiles of a bh on one XCD (K+V = 4 MB/XCD).
// NOTE: NO s_setprio here — in this barrier-coupled 4-wave structure it
// starved the prio-0 STAGE phase and doubled the runtime (round-2 lesson).
__global__ __launch_bounds__(256, 4) void attn(
    const _Float16* __restrict__ Qb, const _Float16* __restrict__ Kb,
    const _Float16* __restrict__ Vtb, const _Float16* __restrict__ biasT,
    float* __restrict__ out) {
    const int wg  = (blockIdx.y << 4) | blockIdx.x;   // linear dispatch id
    const int nid = ((wg & 7) << 7) | (wg >> 3);      // bijective: 128 wg/XCD
    const int bh = nid >> 4;
    const int qt = nid & 15;
    const int b = bh >> 4, h = bh & 15;
    const int tid = threadIdx.x;
    const int wv = tid >> 6, lane = tid & 63;
    const int quad = lane >> 4, l15 = lane & 15;

    __shared__ _Float16 Ks[2][64 * 64];   // [buf][key][d], swizzled
    __shared__ _Float16 Vs[2][64 * 64];   // [buf][d][key], swizzled

    const int q0 = qt * 128 + wv * 32;
    const int Q16a = q0 >> 4;             // + tm

    const _Float16* Qp = Qb + (size_t)(b * HEADS + h) * SEQ * HDIM;
    const _Float16* Kp = Kb + (size_t)(b * HEADS + h) * SEQ * HDIM;
    const _Float16* Vp = Vtb + (size_t)(b * HEADS + h) * HDIM * SEQ;
    const _Float16* Bbase = biasT + (size_t)b * 128 * 128 * 64 * 4;

    // Q fragments (B-operand: lane l15 = qrow, k = d); Q is pre-scaled by SCL
    v8h qf[2][2];
#pragma unroll
    for (int tm = 0; tm < 2; tm++)
#pragma unroll
        for (int kc = 0; kc < 2; kc++)
            qf[tm][kc] = *(const v8h*)&Qp[(size_t)(q0 + tm * 16 + l15) * HDIM + kc * 32 + quad * 8];

    v4f oacc[2][4];
#pragma unroll
    for (int i = 0; i < 2; i++)
#pragma unroll
        for (int j = 0; j < 4; j++) oacc[i][j] = (v4f){0.f, 0.f, 0.f, 0.f};
    float lsum[2] = {0.f, 0.f};

    const int srow = lane >> 3, schk = lane & 7;

#define STAGE(buf_, key0_)                                                  \
    {                                                                       \
        _Pragma("unroll")                                                   \
        for (int i_ = 0; i_ < 2; i_++) {                                    \
            int r_ = wv * 16 + i_ * 8 + srow;                               \
            int c_ = schk ^ (r_ & 7);                                       \
            async16(Kp + (size_t)((key0_) + r_) * HDIM + c_ * 8,            \
                    &Ks[buf_][(wv * 16 + i_ * 8) * 64]);                    \
            async16(Vp + (size_t)r_ * SEQ + (key0_) + c_ * 8,               \
                    &Vs[buf_][(wv * 16 + i_ * 8) * 64]);                    \
        }                                                                   \
    }

#define BLOAD(key0_)                                                        \
    {                                                                       \
        _Pragma("unroll")                                                   \
        for (int nt_ = 0; nt_ < 4; nt_++)                                   \
            _Pragma("unroll")                                               \
            for (int tm_ = 0; tm_ < 2; tm_++)                               \
                bl[nt_][tm_] = *(const int2*)&Bbase[((((size_t)((key0_) >> 4) + nt_) * 128 + Q16a + tm_) * 64 + lane) * 4]; \
    }

    int2 bl[4][2];
    STAGE(0, 0)
    BLOAD(0)
    __syncthreads();     // vmcnt(0) drain: tile 0 + bias 0 in flight -> ready

    for (int kt = 0; kt < SEQ / 64; kt++) {
        const int cur = kt & 1;
        const int key0 = kt * 64;

        // consume bias regs -> accumulator init (f16 pre-multiplied by log2e)
        v4f sacc[4][2];
#pragma unroll
        for (int nt = 0; nt < 4; nt++)
#pragma unroll
            for (int tm = 0; tm < 2; tm++) {
                v4h bv = __builtin_bit_cast(v4h, bl[nt][tm]);
                sacc[nt][tm] = (v4f){(float)bv[0], (float)bv[1], (float)bv[2], (float)bv[3]};
            }

        // prefetch NEXT tile under current compute: K/V -> LDS buf^1 (async),
        // bias -> regs (bl just died into sacc). Latency hides under MFMAs.
        if (kt + 1 < SEQ / 64) {
            STAGE(cur ^ 1, key0 + 64)
            BLOAD(key0 + 64)
        }

        // S^T = K Q^T + bias : C/D row = key (quad*4+r), col = qrow (l15)
#pragma unroll
        for (int kc = 0; kc < 2; kc++) {
            v8h kfr[4];
#pragma unroll
            for (int nt = 0; nt < 4; nt++)
                kfr[nt] = *(const v8h*)&Ks[cur][SWZ(nt * 16 + l15, kc * 4 + quad)];
#pragma unroll
            for (int nt = 0; nt < 4; nt++)
#pragma unroll
                for (int tm = 0; tm < 2; tm++)
                    sacc[nt][tm] = MFMA16(kfr[nt], qf[tm][kc], sacc[nt][tm]);
        }

        // p = exp2(sacc); pack pairs -> PV A-fragments (in registers!)
        int2 pfr[4][2];   // [key-16-tile][tm]: 4 f16, k = quad*4 + j
#pragma unroll
        for (int nt = 0; nt < 4; nt++)
#pragma unroll
            for (int tm = 0; tm < 2; tm++) {
                float p0 = __builtin_amdgcn_exp2f(sacc[nt][tm][0]);
                float p1 = __builtin_amdgcn_exp2f(sacc[nt][tm][1]);
                float p2 = __builtin_amdgcn_exp2f(sacc[nt][tm][2]);
                float p3 = __builtin_amdgcn_exp2f(sacc[nt][tm][3]);
                int2 pkv;
                pkv.x = pk2(p0, p1);
                pkv.y = pk2(p2, p3);
                lsum[tm] += (p0 + p1) + (p2 + p3);
                pfr[nt][tm] = pkv;
            }

        // O += P V via 16x16x16: A = pfr (regs), B = V^T b64 frags from LDS
        // (B-frag: lane l15 = d, k = g*16 + quad*4 + j)
#pragma unroll
        for (int g = 0; g < 4; g++) {
            v4h vfr[4];
#pragma unroll
            for (int nt = 0; nt < 4; nt++) {
                int row = nt * 16 + l15;                       // d
                int cc = g * 2 + (quad >> 1);                  // 16B chunk
                vfr[nt] = *(const v4h*)&Vs[cur][row * 64 + ((cc ^ (row & 7)) * 8) + (quad & 1) * 4];
            }
#pragma unroll
            for (int tm = 0; tm < 2; tm++) {
                v4h pa = __builtin_bit_cast(v4h, pfr[g][tm]);
#pragma unroll
                for (int nt = 0; nt < 4; nt++)
                    oacc[tm][nt] = MFMA16K16(pa, vfr[nt], oacc[tm][nt]);
            }
        }

        // ONE barrier per tile: compiler emits s_waitcnt vmcnt(0) lgkmcnt(0)
        // before s_barrier -> prefetch writes landed AND all waves done
        // reading buf[cur]; buf[cur] is then safe to overwrite next iter.
        __syncthreads();
    }

#undef STAGE
#undef BLOAD

    // epilogue: reduce row sums across quads, fetch per-C/D-row inverse, store
#pragma unroll
    for (int tm = 0; tm < 2; tm++) {
        float lt = lsum[tm];
        lt += __shfl_xor(lt, 16);
        lt += __shfl_xor(lt, 32);
        float inv[4];
#pragma unroll
        for (int r = 0; r < 4; r++)
            inv[r] = 1.0f / __shfl(lt, quad * 4 + r);
#pragma unroll
        for (int nt = 0; nt < 4; nt++)
#pragma unroll
            for (int r = 0; r < 4; r++) {
                int q = q0 + tm * 16 + quad * 4 + r;
                int d = nt * 16 + l15;
                out[((size_t)b * SEQ + q) * HID + h * HDIM + d] = oacc[tm][nt][r] * inv[r];
            }
    }
}

// ---------------- launch ----------------
extern "C" void kernel_launch(void* const* d_in, const int* in_sizes, int n_in,
                              void* d_out, int out_size, void* d_ws, size_t ws_size,
                              hipStream_t stream) {
    const float* x    = (const float*)d_in[0];
    const float* tiv  = (const float*)d_in[1];
    const int*   msk  = (const int*)d_in[2];
    const float* Wq   = (const float*)d_in[3];
    const float* bq   = (const float*)d_in[4];
    const float* Wk   = (const float*)d_in[5];
    const float* bk   = (const float*)d_in[6];
    const float* Wv   = (const float*)d_in[7];
    const float* bv   = (const float*)d_in[8];
    const float* alp  = (const float*)d_in[9];

    char* ws = (char*)d_ws;
    const size_t XB_OFF = 0;                                  // 16,777,216 B
    const size_t WT_OFF = XB_OFF + (size_t)MROWS * HID * 2;   // + 6,291,456 B
    const size_t Q_OFF  = WT_OFF + (size_t)3 * HID * HID * 2;
    const size_t K_OFF  = Q_OFF + (size_t)MROWS * HID * 2;
    const size_t V_OFF  = K_OFF + (size_t)MROWS * HID * 2;
    const size_t B_OFF  = V_OFF + (size_t)MROWS * HID * 2;    // biasT: 33,554,432 B

    _Float16* xb   = (_Float16*)(ws + XB_OFF);
    _Float16* wt   = (_Float16*)(ws + WT_OFF);
    _Float16* Qb   = (_Float16*)(ws + Q_OFF);
    _Float16* Kb   = (_Float16*)(ws + K_OFF);
    _Float16* Vtb  = (_Float16*)(ws + V_OFF);
    _Float16* bias = (_Float16*)(ws + B_OFF);

    prep<<<4096 + 3072, 256, 0, stream>>>(x, xb, Wq, Wk, Wv, wt);
    gemm_bias<<<1536 + 4096, 256, 0, stream>>>(xb, wt, bq, bk, bv, Qb, Kb, Vtb,
                                               tiv, msk, alp, bias);
    attn<<<dim3(SEQ / 128, BATCH * HEADS), 256, 0, stream>>>(Qb, Kb, Vtb, bias,
                                                             (float*)d_out);
}

// Round 4
// 364.496 us; speedup vs baseline: 1.2312x; 1.0329x over previous
//
#include <hip/hip_runtime.h>
#include <hip/hip_bf16.h>
#include <hip/hip_fp16.h>

// Problem constants
#define BATCH 4
#define SEQ   2048
#define HID   1024
#define HEADS 16
#define HDIM  64
#define MROWS (BATCH * SEQ)   // 8192
#define LOG2E 1.4426950408889634f
#define SCL   (LOG2E / 8.0f)  // log2e / sqrt(HDIM)

typedef _Float16 v8h __attribute__((ext_vector_type(8)));
typedef _Float16 v4h __attribute__((ext_vector_type(4)));
typedef _Float16 v2h __attribute__((ext_vector_type(2)));
typedef float    v4f __attribute__((ext_vector_type(4)));
typedef int      v4i __attribute__((ext_vector_type(4)));

#define MFMA16(a, b, c) __builtin_amdgcn_mfma_f32_16x16x32_f16((a), (b), (c), 0, 0, 0)
// 16x16x16 f16 MFMA: A-frag layout (m=lane&15, k=quad*4+j) == S^T C/D layout,
// so exp(S^T) packs directly into PV A-fragments with NO LDS round-trip.
#define MFMA16K16(a, b, c) __builtin_amdgcn_mfma_f32_16x16x16f16((a), (b), (c), 0, 0, 0)

__device__ inline int pk2(float a, float b) {
    return __builtin_bit_cast(int, __builtin_amdgcn_cvt_pkrtz(a, b));
}

// async global->LDS, 16B per lane; dest = wave-uniform base + lane*16
__device__ __forceinline__ void async16(const void* g, void* l) {
    __builtin_amdgcn_global_load_lds(
        (const __attribute__((address_space(1))) unsigned int*)g,
        (__attribute__((address_space(3))) unsigned int*)l, 16, 0, 0);
}

// swizzled LDS element offset for a 64-elem (128B) row: 16B chunk ^= row&7
#define SWZ(row, chunk) (((row) * 64) + ((((chunk) ^ ((row) & 7))) * 8))

// ---------------- fused prep: cvt_x (bid<4096) + transw (bid>=4096) -----
// cvt_x: x f32 -> f16, 8 elems/thread.
// transw: W [K][N] f32 -> Wt [N][K] f16 (3 mats).
__global__ __launch_bounds__(256) void prep(
    const float* __restrict__ x, _Float16* __restrict__ xb,
    const float* __restrict__ W0, const float* __restrict__ W1,
    const float* __restrict__ W2, _Float16* __restrict__ Wt) {
    __shared__ float t[32][33];
    const int bid = blockIdx.x;
    const int tid = threadIdx.x;
    if (bid < 4096) {
        int i = bid * 256 + tid;     // one thread = 8 elems
        const float4* xp = (const float4*)x;
        float4 a = xp[2 * i];
        float4 b = xp[2 * i + 1];
        v4i o;
        o[0] = pk2(a.x, a.y); o[1] = pk2(a.z, a.w);
        o[2] = pk2(b.x, b.y); o[3] = pk2(b.z, b.w);
        ((v4i*)xb)[i] = o;
    } else {
        int tt = bid - 4096;                 // 0..3071
        int z = tt >> 10;
        int rem = tt & 1023;
        const float* W = (z == 0) ? W0 : (z == 1 ? W1 : W2);
        _Float16* dst = Wt + (size_t)z * HID * HID;
        int bx = (rem & 31) * 32, by = (rem >> 5) * 32;
        int tx = tid & 31, ty = tid >> 5;    // (32, 8)
#pragma unroll
        for (int i = 0; i < 4; i++)
            t[ty + i * 8][tx] = W[(size_t)(by + ty + i * 8) * HID + bx + tx];
        __syncthreads();
#pragma unroll
        for (int i = 0; i < 4; i++)
            dst[(size_t)(bx + ty + i * 8) * HID + by + tx] = (_Float16)t[tx][ty + i * 8];
    }
}

// ---------------- fused QKV GEMM + bias build ---------------------------
// bid < 1536 : QKV projection GEMM, double-buffered 2-phase pipeline
//   (prefetch K-step k+1 under compute of k, ONE barrier per step) with
//   bijective XCD chunking: 192 consecutive (m-major) tiles per XCD so the
//   resident set per XCD is ~2MB A-panels + 2MB B = one L2. mode = nid>>9.
// bid >= 1536: mkbias — permuted bias (MFMA S^T fragment order, f16)
//   biasT[b][K16][Q16][lane][r] = mask ? -|a|*log2e*t : -57344
//   (k = K16*16 + (lane>>4)*4 + r, q = Q16*16 + (lane&15))
// gemm blocks at low bids dispatch first (compute-critical); memory-bound
// bias blocks stream into CU slots / HBM BW behind them.
__global__ __launch_bounds__(256) void gemm_bias(
    const _Float16* __restrict__ xb, const _Float16* __restrict__ wt,
    const float* __restrict__ bq, const float* __restrict__ bk,
    const float* __restrict__ bv,
    _Float16* __restrict__ Qb, _Float16* __restrict__ Kb, _Float16* __restrict__ Vtb,
    const float* __restrict__ tiv, const int* __restrict__ msk,
    const float* __restrict__ alphap, _Float16* __restrict__ biasT) {
    __shared__ _Float16 smem[2 * 2 * 128 * 64];   // gemm: As[2]+Bs[2] (64KB); bias: L
    const int bid = blockIdx.x;
    const int tid = threadIdx.x;

    if (bid < 1536) {
        // ---------------- GEMM path (2-phase dbuf) ----------------
        const int nid = (bid & 7) * 192 + (bid >> 3);   // XCD chunk, bijective
        const int mode = nid >> 9;
        const int within = nid & 511;
        const int n0 = (within & 7) * 128;
        const int m0 = (within >> 3) * 128;
        const _Float16* w = wt + (size_t)mode * HID * HID;
        _Float16 (*As)[128 * 64] = (_Float16(*)[128 * 64])smem;
        _Float16 (*Bs)[128 * 64] = (_Float16(*)[128 * 64])(smem + 2 * 128 * 64);
        const int wv = tid >> 6, lane = tid & 63;
        const int quad = lane >> 4, l15 = lane & 15;
        const int wr = wv >> 1, wc = wv & 1;

        v4f acc[4][4];
#pragma unroll
        for (int i = 0; i < 4; i++)
#pragma unroll
            for (int j = 0; j < 4; j++) acc[i][j] = (v4f){0.f, 0.f, 0.f, 0.f};

        const int srow = lane >> 3;         // 0..7 within 8-row chunk
        const int schk = lane & 7;          // 16B chunk within row
        const _Float16* Ag = xb + (size_t)m0 * HID;
        const _Float16* Bg = w + (size_t)n0 * HID;

#define STAGEG(buf_, k0_)                                                   \
        {                                                                   \
            _Pragma("unroll")                                               \
            for (int i_ = 0; i_ < 4; i_++) {                                \
                int ra_ = wv * 32 + i_ * 8 + srow;                          \
                int ca_ = schk ^ (ra_ & 7);                                 \
                async16(Ag + (size_t)ra_ * HID + (k0_) + ca_ * 8,           \
                        &As[buf_][(wv * 32 + i_ * 8) * 64]);                \
                async16(Bg + (size_t)ra_ * HID + (k0_) + ca_ * 8,           \
                        &Bs[buf_][(wv * 32 + i_ * 8) * 64]);                \
            }                                                               \
        }

        STAGEG(0, 0)
        __syncthreads();    // vmcnt(0) drain: step-0 tiles resident

        for (int it = 0; it < HID / 64; it++) {
            const int cur = it & 1;
            // prefetch next K-step under current compute
            if (it + 1 < HID / 64) STAGEG(cur ^ 1, (it + 1) * 64)
#pragma unroll
            for (int kc = 0; kc < 2; kc++) {
                v8h af[4], bf[4];
#pragma unroll
                for (int t = 0; t < 4; t++) {
                    af[t] = *(const v8h*)&As[cur][SWZ(wr * 64 + t * 16 + l15, kc * 4 + quad)];
                    bf[t] = *(const v8h*)&Bs[cur][SWZ(wc * 64 + t * 16 + l15, kc * 4 + quad)];
                }
#pragma unroll
                for (int tm = 0; tm < 4; tm++)
#pragma unroll
                    for (int tn = 0; tn < 4; tn++)
                        acc[tm][tn] = MFMA16(af[tm], bf[tn], acc[tm][tn]);
            }
            // ONE barrier per K-step: drains prefetch (vmcnt0) + all waves
            // done reading buf[cur] before it is overwritten next step.
            __syncthreads();
        }
#undef STAGEG

        const float* pb = (mode == 0) ? bq : (mode == 1 ? bk : bv);
        const float oscl = (mode == 0) ? SCL : 1.0f;   // fold log2e/8 into Q
#pragma unroll
        for (int tm = 0; tm < 4; tm++) {
#pragma unroll
            for (int tn = 0; tn < 4; tn++) {
                int n = n0 + wc * 64 + tn * 16 + l15;
                float bval = pb[n];
                int h = n >> 6, d = n & 63;
#pragma unroll
                for (int r = 0; r < 4; r++) {
                    int m = m0 + wr * 64 + tm * 16 + quad * 4 + r;
                    int b = m >> 11, s = m & 2047;
                    _Float16 hv = (_Float16)((acc[tm][tn][r] + bval) * oscl);
                    if (mode == 2) {
                        Vtb[(((size_t)(b * HEADS + h) * HDIM + d) * SEQ) + s] = hv;
                    } else {
                        _Float16* dst = (mode == 0) ? Qb : Kb;
                        dst[((size_t)(b * HEADS + h) * SEQ + s) * HDIM + d] = hv;
                    }
                }
            }
        }
    } else {
        // ---------------- mkbias path ----------------
        const int t = bid - 1536;                 // 0..4095
        const int kc0 = (t & 7) * 256;
        const int Q16 = (t >> 3) & 127;
        const int b = t >> 10;
        _Float16* L = smem;                        // 16*264 elems
        const float ca = -fabsf(alphap[0]) * LOG2E;
        const int prow = tid >> 6;          // 0..3
        const int pcol = (tid & 63) * 4;    // 0..252
#pragma unroll
        for (int pi = 0; pi < 4; pi++) {
            int r = pi * 4 + prow;
            size_t g = ((size_t)b * SEQ + Q16 * 16 + r) * SEQ + kc0 + pcol;
            float4 tv = *(const float4*)(tiv + g);
            int4   mv = *(const int4*)(msk + g);
            float f0 = mv.x ? ca * tv.x : -57344.0f;
            float f1 = mv.y ? ca * tv.y : -57344.0f;
            float f2 = mv.z ? ca * tv.z : -57344.0f;
            float f3 = mv.w ? ca * tv.w : -57344.0f;
            int2 o; o.x = pk2(f0, f1); o.y = pk2(f2, f3);
            *(int2*)&L[r * 264 + pcol] = o;
        }
        __syncthreads();
        const int lane = tid & 63, tq = tid >> 6;
#pragma unroll
        for (int it = 0; it < 4; it++) {
            int K16i = it * 4 + tq;
            int kl = K16i * 16 + (lane >> 4) * 4;
            int qr = lane & 15;
            int2 v = *(const int2*)&L[qr * 264 + kl];
            size_t o = ((((size_t)b * 128 + (kc0 >> 4) + K16i) * 128 + Q16) * 64 + lane) * 4;
            *(int2*)&biasT[o] = v;
        }
    }
}

// ---------------- flash attention (S^T, P stays in registers) -----------
// grid (16 q-tiles, 64 b*h); block 256 (4 waves); wave owns 32 q-rows.
// 2-phase pipeline: K/V double-buffered in LDS, next tile's async16 +
// bias register loads issued BEFORE current tile's compute; ONE barrier
// per K-tile (its vmcnt(0) drain doubles as the pipeline wait).
// XCD-aware remap keeps all 16 q-tiles of a bh on one XCD (K+V = 4 MB/XCD).
// NOTE: NO s_setprio here — in this barrier-coupled 4-wave structure it
// starved the prio-0 STAGE phase and doubled the runtime (round-2 lesson).
__global__ __launch_bounds__(256, 4) void attn(
    const _Float16* __restrict__ Qb, const _Float16* __restrict__ Kb,
    const _Float16* __restrict__ Vtb, const _Float16* __restrict__ biasT,
    float* __restrict__ out) {
    const int wg  = (blockIdx.y << 4) | blockIdx.x;   // linear dispatch id
    const int nid = ((wg & 7) << 7) | (wg >> 3);      // bijective: 128 wg/XCD
    const int bh = nid >> 4;
    const int qt = nid & 15;
    const int b = bh >> 4, h = bh & 15;
    const int tid = threadIdx.x;
    const int wv = tid >> 6, lane = tid & 63;
    const int quad = lane >> 4, l15 = lane & 15;

    __shared__ _Float16 Ks[2][64 * 64];   // [buf][key][d], swizzled
    __shared__ _Float16 Vs[2][64 * 64];   // [buf][d][key], swizzled

    const int q0 = qt * 128 + wv * 32;
    const int Q16a = q0 >> 4;             // + tm

    const _Float16* Qp = Qb + (size_t)(b * HEADS + h) * SEQ * HDIM;
    const _Float16* Kp = Kb + (size_t)(b * HEADS + h) * SEQ * HDIM;
    const _Float16* Vp = Vtb + (size_t)(b * HEADS + h) * HDIM * SEQ;
    const _Float16* Bbase = biasT + (size_t)b * 128 * 128 * 64 * 4;

    // Q fragments (B-operand: lane l15 = qrow, k = d); Q is pre-scaled by SCL
    v8h qf[2][2];
#pragma unroll
    for (int tm = 0; tm < 2; tm++)
#pragma unroll
        for (int kc = 0; kc < 2; kc++)
            qf[tm][kc] = *(const v8h*)&Qp[(size_t)(q0 + tm * 16 + l15) * HDIM + kc * 32 + quad * 8];

    v4f oacc[2][4];
#pragma unroll
    for (int i = 0; i < 2; i++)
#pragma unroll
        for (int j = 0; j < 4; j++) oacc[i][j] = (v4f){0.f, 0.f, 0.f, 0.f};
    float lsum[2] = {0.f, 0.f};

    const int srow = lane >> 3, schk = lane & 7;

#define STAGE(buf_, key0_)                                                  \
    {                                                                       \
        _Pragma("unroll")                                                   \
        for (int i_ = 0; i_ < 2; i_++) {                                    \
            int r_ = wv * 16 + i_ * 8 + srow;                               \
            int c_ = schk ^ (r_ & 7);                                       \
            async16(Kp + (size_t)((key0_) + r_) * HDIM + c_ * 8,            \
                    &Ks[buf_][(wv * 16 + i_ * 8) * 64]);                    \
            async16(Vp + (size_t)r_ * SEQ + (key0_) + c_ * 8,               \
                    &Vs[buf_][(wv * 16 + i_ * 8) * 64]);                    \
        }                                                                   \
    }

#define BLOAD(key0_)                                                        \
    {                                                                       \
        _Pragma("unroll")                                                   \
        for (int nt_ = 0; nt_ < 4; nt_++)                                   \
            _Pragma("unroll")                                               \
            for (int tm_ = 0; tm_ < 2; tm_++)                               \
                bl[nt_][tm_] = *(const int2*)&Bbase[((((size_t)((key0_) >> 4) + nt_) * 128 + Q16a + tm_) * 64 + lane) * 4]; \
    }

    int2 bl[4][2];
    STAGE(0, 0)
    BLOAD(0)
    __syncthreads();     // vmcnt(0) drain: tile 0 + bias 0 in flight -> ready

    for (int kt = 0; kt < SEQ / 64; kt++) {
        const int cur = kt & 1;
        const int key0 = kt * 64;

        // consume bias regs -> accumulator init (f16 pre-multiplied by log2e)
        v4f sacc[4][2];
#pragma unroll
        for (int nt = 0; nt < 4; nt++)
#pragma unroll
            for (int tm = 0; tm < 2; tm++) {
                v4h bv = __builtin_bit_cast(v4h, bl[nt][tm]);
                sacc[nt][tm] = (v4f){(float)bv[0], (float)bv[1], (float)bv[2], (float)bv[3]};
            }

        // prefetch NEXT tile under current compute: K/V -> LDS buf^1 (async),
        // bias -> regs (bl just died into sacc). Latency hides under MFMAs.
        if (kt + 1 < SEQ / 64) {
            STAGE(cur ^ 1, key0 + 64)
            BLOAD(key0 + 64)
        }

        // S^T = K Q^T + bias : C/D row = key (quad*4+r), col = qrow (l15)
#pragma unroll
        for (int kc = 0; kc < 2; kc++) {
            v8h kfr[4];
#pragma unroll
            for (int nt = 0; nt < 4; nt++)
                kfr[nt] = *(const v8h*)&Ks[cur][SWZ(nt * 16 + l15, kc * 4 + quad)];
#pragma unroll
            for (int nt = 0; nt < 4; nt++)
#pragma unroll
                for (int tm = 0; tm < 2; tm++)
                    sacc[nt][tm] = MFMA16(kfr[nt], qf[tm][kc], sacc[nt][tm]);
        }

        // p = exp2(sacc); pack pairs -> PV A-fragments (in registers!)
        int2 pfr[4][2];   // [key-16-tile][tm]: 4 f16, k = quad*4 + j
#pragma unroll
        for (int nt = 0; nt < 4; nt++)
#pragma unroll
            for (int tm = 0; tm < 2; tm++) {
                float p0 = __builtin_amdgcn_exp2f(sacc[nt][tm][0]);
                float p1 = __builtin_amdgcn_exp2f(sacc[nt][tm][1]);
                float p2 = __builtin_amdgcn_exp2f(sacc[nt][tm][2]);
                float p3 = __builtin_amdgcn_exp2f(sacc[nt][tm][3]);
                int2 pkv;
                pkv.x = pk2(p0, p1);
                pkv.y = pk2(p2, p3);
                lsum[tm] += (p0 + p1) + (p2 + p3);
                pfr[nt][tm] = pkv;
            }

        // O += P V via 16x16x16: A = pfr (regs), B = V^T b64 frags from LDS
        // (B-frag: lane l15 = d, k = g*16 + quad*4 + j)
#pragma unroll
        for (int g = 0; g < 4; g++) {
            v4h vfr[4];
#pragma unroll
            for (int nt = 0; nt < 4; nt++) {
                int row = nt * 16 + l15;                       // d
                int cc = g * 2 + (quad >> 1);                  // 16B chunk
                vfr[nt] = *(const v4h*)&Vs[cur][row * 64 + ((cc ^ (row & 7)) * 8) + (quad & 1) * 4];
            }
#pragma unroll
            for (int tm = 0; tm < 2; tm++) {
                v4h pa = __builtin_bit_cast(v4h, pfr[g][tm]);
#pragma unroll
                for (int nt = 0; nt < 4; nt++)
                    oacc[tm][nt] = MFMA16K16(pa, vfr[nt], oacc[tm][nt]);
            }
        }

        // ONE barrier per tile: compiler emits s_waitcnt vmcnt(0) lgkmcnt(0)
        // before s_barrier -> prefetch writes landed AND all waves done
        // reading buf[cur]; buf[cur] is then safe to overwrite next iter.
        __syncthreads();
    }

#undef STAGE
#undef BLOAD

    // epilogue: reduce row sums across quads, fetch per-C/D-row inverse, store
#pragma unroll
    for (int tm = 0; tm < 2; tm++) {
        float lt = lsum[tm];
        lt += __shfl_xor(lt, 16);
        lt += __shfl_xor(lt, 32);
        float inv[4];
#pragma unroll
        for (int r = 0; r < 4; r++)
            inv[r] = 1.0f / __shfl(lt, quad * 4 + r);
#pragma unroll
        for (int nt = 0; nt < 4; nt++)
#pragma unroll
            for (int r = 0; r < 4; r++) {
                int q = q0 + tm * 16 + quad * 4 + r;
                int d = nt * 16 + l15;
                out[((size_t)b * SEQ + q) * HID + h * HDIM + d] = oacc[tm][nt][r] * inv[r];
            }
    }
}

// ---------------- launch ----------------
extern "C" void kernel_launch(void* const* d_in, const int* in_sizes, int n_in,
                              void* d_out, int out_size, void* d_ws, size_t ws_size,
                              hipStream_t stream) {
    const float* x    = (const float*)d_in[0];
    const float* tiv  = (const float*)d_in[1];
    const int*   msk  = (const int*)d_in[2];
    const float* Wq   = (const float*)d_in[3];
    const float* bq   = (const float*)d_in[4];
    const float* Wk   = (const float*)d_in[5];
    const float* bk   = (const float*)d_in[6];
    const float* Wv   = (const float*)d_in[7];
    const float* bv   = (const float*)d_in[8];
    const float* alp  = (const float*)d_in[9];

    char* ws = (char*)d_ws;
    const size_t XB_OFF = 0;                                  // 16,777,216 B
    const size_t WT_OFF = XB_OFF + (size_t)MROWS * HID * 2;   // + 6,291,456 B
    const size_t Q_OFF  = WT_OFF + (size_t)3 * HID * HID * 2;
    const size_t K_OFF  = Q_OFF + (size_t)MROWS * HID * 2;
    const size_t V_OFF  = K_OFF + (size_t)MROWS * HID * 2;
    const size_t B_OFF  = V_OFF + (size_t)MROWS * HID * 2;    // biasT: 33,554,432 B

    _Float16* xb   = (_Float16*)(ws + XB_OFF);
    _Float16* wt   = (_Float16*)(ws + WT_OFF);
    _Float16* Qb   = (_Float16*)(ws + Q_OFF);
    _Float16* Kb   = (_Float16*)(ws + K_OFF);
    _Float16* Vtb  = (_Float16*)(ws + V_OFF);
    _Float16* bias = (_Float16*)(ws + B_OFF);

    prep<<<4096 + 3072, 256, 0, stream>>>(x, xb, Wq, Wk, Wv, wt);
    gemm_bias<<<1536 + 4096, 256, 0, stream>>>(xb, wt, bq, bk, bv, Qb, Kb, Vtb,
                                               tiv, msk, alp, bias);
    attn<<<dim3(SEQ / 128, BATCH * HEADS), 256, 0, stream>>>(Qb, Kb, Vtb, bias,
                                                             (float*)d_out);
}